// Round 6
// baseline (242.263 us; speedup 1.0000x reference)
//
#include <hip/hip_runtime.h>
#include <hip/hip_bf16.h>

// Problem: CausalSelfAttention  B=2, T=2048, C=1024, H=16, D=64
// Round 18: kill the __syncthreads vmcnt(0) drain (T4 counted waits).
// R17 result: bank conflicts 4.19M -> 0 (G21 swizzle verified) but only -2us:
// conflicts were hidden; the drain is the binding constraint. __syncthreads
// compiles to s_waitcnt vmcnt(0) lgkmcnt(0); s_barrier -- (a) GEMM K-loops
// drain their own global_load_lds queue every step (the m97 ~900TF ceiling,
// we're at 777); (b) attn's "prefetch" is drained by the barrier right after
// issue = synchronous load every kt.
// Fix: GEMMs get LDS double-buffer + counted s_waitcnt vmcnt(8|3) + raw
// s_barrier, stage k+2 after compute (no vmcnt(0) in loop). attn gets raw
// barriers + own-wave lgkmcnt(0) before barrier-2; prefetch vmcnt wait now
// lands at next iteration's LDS-write (true T14 overlap).
// Geometry/swizzle/numerics unchanged from R17 (passed, 241.6us, conflicts 0).
// ws (62 MB): Qh 8|Ql 8|Kh 8|Kl 8|xh 8(->Yb)|xl 8(->VT)|WaTh 6|WaTl 6|WpT 2

#define B_  2
#define T_  2048
#define C_  1024
#define H_  16
#define D_  64
#define M_  (B_ * T_)      // 4096
#define N3_ (3 * C_)       // 3072

typedef __attribute__((ext_vector_type(8))) short s16x8;
typedef __attribute__((ext_vector_type(4))) short s16x4;
typedef __attribute__((ext_vector_type(4))) float f32x4;

typedef const __attribute__((address_space(1))) unsigned int gu32_t;
typedef __attribute__((address_space(3))) unsigned int lu32_t;

#define MFMA16(a, b, c) __builtin_amdgcn_mfma_f32_16x16x32_bf16(a, b, c, 0, 0, 0)

__device__ __forceinline__ void gload_lds16(const short* g, short* l) {
    __builtin_amdgcn_global_load_lds((gu32_t*)g, (lu32_t*)l, 16, 0, 0);
}

__device__ __forceinline__ float b2f(unsigned short u) {
    return __uint_as_float(((unsigned)u) << 16);
}
__device__ __forceinline__ unsigned short f2b(float f) {   // RNE bf16 round
    unsigned u = __float_as_uint(f);
    return (unsigned short)((u + 0x7FFFu + ((u >> 16) & 1u)) >> 16);
}
__device__ __forceinline__ float fexp2(float x) {
#if __has_builtin(__builtin_amdgcn_exp2f)
    return __builtin_amdgcn_exp2f(x);
#else
    return exp2f(x);
#endif
}

// ---------------------------------------------------------------------------
// fp32 -> (hi, lo) bf16 split. n multiple of 2048.
// ---------------------------------------------------------------------------
__global__ __launch_bounds__(256) void cvt_split(
    const float* __restrict__ in, short* __restrict__ oh, short* __restrict__ ol, int n)
{
    int i = (blockIdx.x * 256 + threadIdx.x) * 8;
    if (i >= n) return;
    float4 a = *(const float4*)&in[i];
    float4 b = *(const float4*)&in[i + 4];
    float v[8] = {a.x, a.y, a.z, a.w, b.x, b.y, b.z, b.w};
    s16x8 h, l;
    #pragma unroll
    for (int j = 0; j < 8; j++) {
        unsigned short hb = f2b(v[j]);
        h[j] = (short)hb;
        l[j] = (short)f2b(v[j] - b2f(hb));
    }
    *(s16x8*)&oh[i] = h;
    *(s16x8*)&ol[i] = l;
}

// ---------------------------------------------------------------------------
// fp32 [R,Cn] -> (hi,lo) bf16 [Cn,R] transpose+split. grid (Cn/64, R/64).
// ---------------------------------------------------------------------------
__global__ __launch_bounds__(256) void cvtT_split(
    const float* __restrict__ in, short* __restrict__ oh, short* __restrict__ ol,
    int R, int Cn)
{
    __shared__ short th[64][80];
    __shared__ short tl[64][80];
    const int tid = threadIdx.x;
    const int k0 = blockIdx.y * 64;
    const int n0 = blockIdx.x * 64;
    {
        int rl = tid >> 4, cl = (tid & 15) * 4;
        #pragma unroll
        for (int i = 0; i < 4; i++) {
            int kr = rl + i * 16;
            float4 v4 = *(const float4*)&in[(size_t)(k0 + kr) * Cn + n0 + cl];
            float v[4] = {v4.x, v4.y, v4.z, v4.w};
            #pragma unroll
            for (int j = 0; j < 4; j++) {
                unsigned short hb = f2b(v[j]);
                th[cl + j][kr] = (short)hb;
                tl[cl + j][kr] = (short)f2b(v[j] - b2f(hb));
            }
        }
    }
    __syncthreads();
    {
        int ro = tid >> 2, co = (tid & 3) * 16;
        *(s16x8*)&oh[(size_t)(n0 + ro) * R + k0 + co]     = *(s16x8*)&th[ro][co];
        *(s16x8*)&oh[(size_t)(n0 + ro) * R + k0 + co + 8] = *(s16x8*)&th[ro][co + 8];
        *(s16x8*)&ol[(size_t)(n0 + ro) * R + k0 + co]     = *(s16x8*)&tl[ro][co];
        *(s16x8*)&ol[(size_t)(n0 + ro) * R + k0 + co + 8] = *(s16x8*)&tl[ro][co + 8];
    }
}

// ---------------------------------------------------------------------------
// fp32 [R,Cn] -> bf16 [Cn,R] transpose (single, for W_proj).
// ---------------------------------------------------------------------------
__global__ __launch_bounds__(256) void cvtT_bf16(
    const float* __restrict__ in, short* __restrict__ out, int R, int Cn)
{
    __shared__ short t[64][80];
    const int tid = threadIdx.x;
    const int k0 = blockIdx.y * 64;
    const int n0 = blockIdx.x * 64;
    {
        int rl = tid >> 4, cl = (tid & 15) * 4;
        #pragma unroll
        for (int i = 0; i < 4; i++) {
            int kr = rl + i * 16;
            float4 v = *(const float4*)&in[(size_t)(k0 + kr) * Cn + n0 + cl];
            t[cl + 0][kr] = (short)f2b(v.x);
            t[cl + 1][kr] = (short)f2b(v.y);
            t[cl + 2][kr] = (short)f2b(v.z);
            t[cl + 3][kr] = (short)f2b(v.w);
        }
    }
    __syncthreads();
    {
        int ro = tid >> 2, co = (tid & 3) * 16;
        *(s16x8*)&out[(size_t)(n0 + ro) * R + k0 + co]     = *(s16x8*)&t[ro][co];
        *(s16x8*)&out[(size_t)(n0 + ro) * R + k0 + co + 8] = *(s16x8*)&t[ro][co + 8];
    }
}

// ---------------------------------------------------------------------------
// qkv_qk: Q,K columns (N=2048), bf16x3, hi/lo scatter. Q pre-scaled by
// 8*log2(e). 128x128 tile, grid (16,32). LDS 64 KB (double-buffered).
// Counted-vmcnt pipeline: stage k+2 flies under a full compute phase.
// Bank-conflict-free granule swizzle (R17, verified 0 conflicts).
// ---------------------------------------------------------------------------
#define QK_STAGE(buf, kk) do {                                          \
    _Pragma("unroll")                                                   \
    for (int j = 0; j < 2; j++) {                                       \
        int s = wave * 2 + j;                                           \
        int row = s * 16 + gr;                                          \
        size_t ga = (size_t)(m0 + row) * C_ + (kk) + gc;                \
        size_t gb = (size_t)(n0 + row) * C_ + (kk) + gc;                \
        gload_lds16(&Ah[ga],  &Ash[buf][s * 512]);                      \
        gload_lds16(&Al[ga],  &Asl[buf][s * 512]);                      \
        gload_lds16(&BTh[gb], &Bsh[buf][s * 512]);                      \
        gload_lds16(&BTl[gb], &Bsl[buf][s * 512]);                      \
    }                                                                   \
} while (0)

__global__ __launch_bounds__(256) void qkv_qk(
    const short* __restrict__ Ah, const short* __restrict__ Al,
    const short* __restrict__ BTh, const short* __restrict__ BTl,
    const float* __restrict__ bias,
    short* __restrict__ Qh, short* __restrict__ Ql,
    short* __restrict__ Kh, short* __restrict__ Kl)
{
    __shared__ short Ash[2][128 * 32], Asl[2][128 * 32];
    __shared__ short Bsh[2][128 * 32], Bsl[2][128 * 32];   // 64 KB

    const int tid  = threadIdx.x;
    const int wave = tid >> 6, lane = tid & 63;
    const int wm = wave >> 1, wn = wave & 1;
    const int lm = lane & 15, lq = lane >> 4;
    const int m0 = blockIdx.y * 128, n0 = blockIdx.x * 128;
    const int gr  = (lane >> 2);
    // swizzled SOURCE granule: slot (row,g) holds global granule g^((row>>1)&3)
    const int gc  = (((lane & 3) ^ ((lane >> 3) & 3)) << 3);
    // swizzled READ col: logical granule lq of row-in-seg lm lives at lq^((lm>>1)&3)
    const int sg  = ((lq ^ ((lm >> 1) & 3)) << 3);

    f32x4 acc[4][4] = {};

    QK_STAGE(0, 0);
    QK_STAGE(1, 32);

    for (int it = 0; it < 32; ++it) {
        const int cur = it & 1;
        // own stage(k=it) complete (8 newer loads may remain in flight)
        if (it == 31) asm volatile("s_waitcnt vmcnt(0)" ::: "memory");
        else          asm volatile("s_waitcnt vmcnt(8)" ::: "memory");
        __builtin_amdgcn_s_barrier();            // all waves' stage(k=it) done
        __builtin_amdgcn_sched_barrier(0);       // keep ds_reads below barrier

        s16x8 ah[4], al[4], bh[4], bl[4];
        #pragma unroll
        for (int mi = 0; mi < 4; mi++) {
            int r = wm * 64 + mi * 16 + lm;
            ah[mi] = *(const s16x8*)&Ash[cur][r * 32 + sg];
            al[mi] = *(const s16x8*)&Asl[cur][r * 32 + sg];
        }
        #pragma unroll
        for (int nj = 0; nj < 4; nj++) {
            int r = wn * 64 + nj * 16 + lm;
            bh[nj] = *(const s16x8*)&Bsh[cur][r * 32 + sg];
            bl[nj] = *(const s16x8*)&Bsl[cur][r * 32 + sg];
        }
        #pragma unroll
        for (int mi = 0; mi < 4; mi++)
            #pragma unroll
            for (int nj = 0; nj < 4; nj++) {
                acc[mi][nj] = MFMA16(ah[mi], bh[nj], acc[mi][nj]);
                acc[mi][nj] = MFMA16(ah[mi], bl[nj], acc[mi][nj]);
                acc[mi][nj] = MFMA16(al[mi], bh[nj], acc[mi][nj]);
            }

        __builtin_amdgcn_sched_barrier(0);       // ds_reads stay above barrier
        __builtin_amdgcn_s_barrier();            // all waves done reading buf[cur]
        if (it < 30) QK_STAGE(cur, (it + 2) * 32);   // overwrite, flies 1 full iter
    }

    #pragma unroll
    for (int nj = 0; nj < 4; nj++) {
        int n = n0 + wn * 64 + nj * 16 + lm;
        float bv = bias[n];
        int isK = n >> 10;
        int c = n & (C_ - 1);
        int h = c >> 6, d = c & (D_ - 1);
        short* dh = isK ? Kh : Qh;
        short* dl = isK ? Kl : Ql;
        // Q carries sqrt(D)=8 and log2(e): softmax runs in exp2 domain
        float scale = isK ? 1.0f : 11.541560327111708f;   // 8*log2(e)
        #pragma unroll
        for (int mi = 0; mi < 4; mi++) {
            #pragma unroll
            for (int r = 0; r < 4; r++) {
                int m  = m0 + wm * 64 + mi * 16 + lq * 4 + r;
                int bb = m >> 11, t = m & (T_ - 1);
                float v = (acc[mi][nj][r] + bv) * scale;
                size_t idx = (((size_t)bb * H_ + h) * T_ + t) * D_ + d;
                unsigned short hb = f2b(v);
                dh[idx] = (short)hb;
                dl[idx] = (short)f2b(v - b2f(hb));
            }
        }
    }
}

// ---------------------------------------------------------------------------
// qkv_v: V columns (N=1024), single bf16, scatter TRANSPOSED -> VT [B,H,D,T].
// 64x128 tile, grid (8,64). LDS 24 KB dbuf, counted-vmcnt pipeline.
// ---------------------------------------------------------------------------
#define V_STAGE(buf, kk) do {                                           \
    {                                                                   \
        int rowA = wave * 16 + gr;                                      \
        gload_lds16(&Ah[(size_t)(m0 + rowA) * C_ + (kk) + gc],          \
                    &Ash[buf][wave * 512]);                             \
        _Pragma("unroll")                                               \
        for (int j = 0; j < 2; j++) {                                   \
            int s = wave * 2 + j;                                       \
            int rowB = s * 16 + gr;                                     \
            gload_lds16(&BTh[(size_t)(n0 + rowB) * C_ + (kk) + gc],     \
                        &Bsh[buf][s * 512]);                            \
        }                                                               \
    }                                                                   \
} while (0)

__global__ __launch_bounds__(256, 4) void qkv_v(
    const short* __restrict__ Ah, const short* __restrict__ BTh,
    const float* __restrict__ bias, short* __restrict__ VT)
{
    __shared__ short Ash[2][64 * 32];    // 8 KB
    __shared__ short Bsh[2][128 * 32];   // 16 KB

    const int tid  = threadIdx.x;
    const int wave = tid >> 6, lane = tid & 63;
    const int wm = wave >> 1, wn = wave & 1;
    const int lm = lane & 15, lq = lane >> 4;
    const int m0 = blockIdx.y * 64, n0 = blockIdx.x * 128;
    const int gr  = (lane >> 2);
    const int gc  = (((lane & 3) ^ ((lane >> 3) & 3)) << 3);
    const int sg  = ((lq ^ ((lm >> 1) & 3)) << 3);

    f32x4 acc[2][4] = {};

    V_STAGE(0, 0);
    V_STAGE(1, 32);

    for (int it = 0; it < 32; ++it) {
        const int cur = it & 1;
        if (it == 31) asm volatile("s_waitcnt vmcnt(0)" ::: "memory");
        else          asm volatile("s_waitcnt vmcnt(3)" ::: "memory");
        __builtin_amdgcn_s_barrier();
        __builtin_amdgcn_sched_barrier(0);

        s16x8 af[2], bfr[4];
        #pragma unroll
        for (int mi = 0; mi < 2; mi++)
            af[mi] = *(const s16x8*)&Ash[cur][(wm * 32 + mi * 16 + lm) * 32 + sg];
        #pragma unroll
        for (int nj = 0; nj < 4; nj++)
            bfr[nj] = *(const s16x8*)&Bsh[cur][(wn * 64 + nj * 16 + lm) * 32 + sg];
        #pragma unroll
        for (int mi = 0; mi < 2; mi++)
            #pragma unroll
            for (int nj = 0; nj < 4; nj++)
                acc[mi][nj] = MFMA16(af[mi], bfr[nj], acc[mi][nj]);

        __builtin_amdgcn_sched_barrier(0);
        __builtin_amdgcn_s_barrier();
        if (it < 30) V_STAGE(cur, (it + 2) * 32);
    }

    #pragma unroll
    for (int nj = 0; nj < 4; nj++) {
        int n = n0 + wn * 64 + nj * 16 + lm;    // [0, 1024) V channel
        float bv = bias[n];
        int h = n >> 6, d = n & (D_ - 1);
        #pragma unroll
        for (int mi = 0; mi < 2; mi++) {
            #pragma unroll
            for (int r = 0; r < 4; r++) {
                int m  = m0 + wm * 32 + mi * 16 + lq * 4 + r;
                int bb = m >> 11, t = m & (T_ - 1);
                VT[(((size_t)bb * H_ + h) * D_ + d) * T_ + t] =
                    (short)f2b(acc[mi][nj][r] + bv);
            }
        }
    }
}

// ---------------------------------------------------------------------------
// proj: out fp32 [M,C] = Yb(bf16) @ WpT(bf16) + bias. 64x128 tile, grid 512.
// LDS 24 KB dbuf, counted-vmcnt pipeline.
// ---------------------------------------------------------------------------
__global__ __launch_bounds__(256, 4) void proj_mfma(
    const short* __restrict__ Ah, const short* __restrict__ BTh,
    const float* __restrict__ bias, float* __restrict__ out)
{
    __shared__ short Ash[2][64 * 32];
    __shared__ short Bsh[2][128 * 32];

    const int tid  = threadIdx.x;
    const int wave = tid >> 6, lane = tid & 63;
    const int wm = wave >> 1, wn = wave & 1;
    const int lm = lane & 15, lq = lane >> 4;
    const int m0 = blockIdx.y * 64, n0 = blockIdx.x * 128;
    const int gr  = (lane >> 2);
    const int gc  = (((lane & 3) ^ ((lane >> 3) & 3)) << 3);
    const int sg  = ((lq ^ ((lm >> 1) & 3)) << 3);

    f32x4 acc[2][4] = {};

    V_STAGE(0, 0);
    V_STAGE(1, 32);

    for (int it = 0; it < 32; ++it) {
        const int cur = it & 1;
        if (it == 31) asm volatile("s_waitcnt vmcnt(0)" ::: "memory");
        else          asm volatile("s_waitcnt vmcnt(3)" ::: "memory");
        __builtin_amdgcn_s_barrier();
        __builtin_amdgcn_sched_barrier(0);

        s16x8 af[2], bfr[4];
        #pragma unroll
        for (int mi = 0; mi < 2; mi++)
            af[mi] = *(const s16x8*)&Ash[cur][(wm * 32 + mi * 16 + lm) * 32 + sg];
        #pragma unroll
        for (int nj = 0; nj < 4; nj++)
            bfr[nj] = *(const s16x8*)&Bsh[cur][(wn * 64 + nj * 16 + lm) * 32 + sg];
        #pragma unroll
        for (int mi = 0; mi < 2; mi++)
            #pragma unroll
            for (int nj = 0; nj < 4; nj++)
                acc[mi][nj] = MFMA16(af[mi], bfr[nj], acc[mi][nj]);

        __builtin_amdgcn_sched_barrier(0);
        __builtin_amdgcn_s_barrier();
        if (it < 30) V_STAGE(cur, (it + 2) * 32);
    }

    #pragma unroll
    for (int nj = 0; nj < 4; nj++) {
        int n = n0 + wn * 64 + nj * 16 + lm;
        float bv = bias[n];
        #pragma unroll
        for (int mi = 0; mi < 2; mi++) {
            #pragma unroll
            for (int r = 0; r < 4; r++) {
                int m = m0 + wm * 32 + mi * 16 + lq * 4 + r;
                out[(size_t)m * C_ + n] = acc[mi][nj][r] + bv;
            }
        }
    }
}

// ---------------------------------------------------------------------------
// online softmax (exp2 domain) with defer-max (THR=8). S in/out: S^T frag,
// per-thread 16 values for q-row lm. On exit S holds P = exp2(S - m).
// ---------------------------------------------------------------------------
__device__ __forceinline__ void online_sm(
    f32x4 S[4], float& mrow, float& lrow, f32x4 O[4], int quad)
{
    float v[16];
    #pragma unroll
    for (int t = 0; t < 4; t++)
        #pragma unroll
        for (int r = 0; r < 4; r++) v[t * 4 + r] = S[t][r];
    #pragma unroll
    for (int s = 8; s; s >>= 1)
        #pragma unroll
        for (int i = 0; i < s; i++) v[i] = fmaxf(v[i], v[i + s]);
    float rm = v[0];
    rm = fmaxf(rm, __shfl_xor(rm, 16, 64));
    rm = fmaxf(rm, __shfl_xor(rm, 32, 64));
    // defer-max: only rescale when some row grew by > 8 (=2^8 headroom)
    if (!__all(rm - mrow <= 8.f)) {
        float mnew  = fmaxf(mrow, rm);
        float alpha = fexp2(mrow - mnew);
        mrow = mnew;
        lrow *= alpha;
        float al[4];
        #pragma unroll
        for (int r = 0; r < 4; r++) al[r] = __shfl(alpha, quad * 4 + r, 64);
        #pragma unroll
        for (int t = 0; t < 4; t++)
            #pragma unroll
            for (int r = 0; r < 4; r++) O[t][r] *= al[r];
    }
    float sv[16];
    #pragma unroll
    for (int t = 0; t < 4; t++)
        #pragma unroll
        for (int r = 0; r < 4; r++) {
            float p = fexp2(S[t][r] - mrow);
            S[t][r] = p;
            sv[t * 4 + r] = p;
        }
    #pragma unroll
    for (int s = 8; s; s >>= 1)
        #pragma unroll
        for (int i = 0; i < s; i++) sv[i] += sv[i + s];
    float rs = sv[0];
    rs += __shfl_xor(rs, 16, 64);
    rs += __shfl_xor(rs, 32, 64);
    lrow += rs;
}

// ---------------------------------------------------------------------------
// MFMA flash attention, S^T layout, PAIRED q-tiles per block. Grid 512.
// Raw barriers: prefetch loads issued between barriers now FLY across the
// compute phase (their vmcnt wait lands at next iteration's LDS-write).
// Own-wave lgkmcnt(0) before barrier-2 makes ds_writes visible block-wide.
// LDS 40KB, XOR-swizzled, 2 blocks/CU. Defer-max softmax in exp2 domain.
// ---------------------------------------------------------------------------
__global__ __launch_bounds__(256, 2) void attn_mfma(
    const short* __restrict__ Qh, const short* __restrict__ Ql,
    const short* __restrict__ Kh, const short* __restrict__ Kl,
    const short* __restrict__ VT, short* __restrict__ Yb)
{
    __shared__ short Ksh[64][64], Ksl[64][64];   // [key][d], XOR-swizzled
    __shared__ short Vt [64][64];                // [d][key], XOR-swizzled
    __shared__ short Ps [4][2][16][64];          // per-wave P slabs (B=0,A=1)

    const int tid  = threadIdx.x;
    const int wave = tid >> 6, lane = tid & 63;
    const int lm   = lane & 15, quad = lane >> 4;
    const int swz  = (lm & 7) << 3;              // read-side XOR (shorts)

    const int bid = blockIdx.x;                  // 512 blocks
    const int xcd = bid & 7;
    const int r_  = bid >> 3;                    // 0..63 per XCD
    const int bhl = r_ & 3;
    const int u   = r_ >> 2;                     // 0..15
    const int g_  = u >> 3, j_ = u & 7;
    const int j   = g_ ? (15 - j_) : j_;         // CU slot pairs j with 15-j
    const int bh  = xcd * 4 + bhl;
    const int b   = bh >> 4, h = bh & (H_ - 1);
    const int qtA = j, qtB = 31 - j;
    const int q0A = qtA * 64, q0B = qtB * 64;
    const size_t base  = (size_t)bh * T_ * D_;   // Q,K: [b,h,t,d]
    const size_t vbase = (size_t)bh * D_ * T_;   // VT:  [b,h,d,t]

    const int src = tid >> 3;                    // staging row 0..31 (+32)
    const int sch = (tid & 7) * 8;               // linear global col (shorts)
    const int wsw = sch ^ ((src & 7) << 3);      // swizzled LDS write col

    // ---- Q frags direct from global (L2-hit, once per block) ----
    s16x8 bqhA[2], bqlA[2], bqhB[2], bqlB[2];
    #pragma unroll
    for (int kc = 0; kc < 2; kc++) {
        size_t ga = base + (size_t)(q0A + wave * 16 + lm) * D_ + kc * 32 + quad * 8;
        size_t gb = base + (size_t)(q0B + wave * 16 + lm) * D_ + kc * 32 + quad * 8;
        bqhA[kc] = *(const s16x8*)&Qh[ga];
        bqlA[kc] = *(const s16x8*)&Ql[ga];
        bqhB[kc] = *(const s16x8*)&Qh[gb];
        bqlB[kc] = *(const s16x8*)&Ql[gb];
    }

    // ---- prefetch k-tile 0 into registers ----
    s16x8 pkh[2], pkl[2], pvt[2];
    #pragma unroll
    for (int i = 0; i < 2; i++) {
        int row = i * 32 + src;
        size_t gk = base + (size_t)row * D_ + sch;
        pkh[i] = *(const s16x8*)&Kh[gk];
        pkl[i] = *(const s16x8*)&Kl[gk];
        pvt[i] = *(const s16x8*)&VT[vbase + (size_t)row * T_ + sch];
    }

    float mA = -INFINITY, lA = 0.f;
    float mB = -INFINITY, lB = 0.f;
    f32x4 OA[4] = {}, OB[4] = {};

    for (int kt = 0; kt <= qtB; kt++) {
        __builtin_amdgcn_s_barrier();             // WAR: prev readers arrived
        #pragma unroll
        for (int i = 0; i < 2; i++) {             // VGPR -> LDS (swizzled)
            int row = i * 32 + src;
            *(s16x8*)&Ksh[row][wsw] = pkh[i];
            *(s16x8*)&Ksl[row][wsw] = pkl[i];
            *(s16x8*)&Vt [row][wsw] = pvt[i];
        }
        if (kt < qtB) {                           // issue next tile's loads
            #pragma unroll
            for (int i = 0; i < 2; i++) {
                int row = i * 32 + src;
                size_t gk = base + (size_t)((kt + 1) * 64 + row) * D_ + sch;
                pkh[i] = *(const s16x8*)&Kh[gk];
                pkl[i] = *(const s16x8*)&Kl[gk];
                pvt[i] = *(const s16x8*)&VT[vbase + (size_t)row * T_ + (kt + 1) * 64 + sch];
            }
        }
        asm volatile("s_waitcnt lgkmcnt(0)" ::: "memory");  // my ds_writes done
        __builtin_amdgcn_s_barrier();             // RAW: all writes visible
        __builtin_amdgcn_sched_barrier(0);        // keep reads below barrier

        const bool doA = (kt <= qtA);
        const int  qg  = wave * 16 + lm;

        f32x4 SB[4] = {}, SA[4] = {};
        if (doA) {
            // dual: one k-frag read feeds 6 MFMAs (two independent chains)
            #pragma unroll
            for (int t = 0; t < 4; t++)
                #pragma unroll
                for (int kc = 0; kc < 2; kc++) {
                    s16x8 kh8 = *(const s16x8*)&Ksh[t * 16 + lm][(kc * 32 + quad * 8) ^ swz];
                    s16x8 kl8 = *(const s16x8*)&Ksl[t * 16 + lm][(kc * 32 + quad * 8) ^ swz];
                    SB[t] = MFMA16(kh8, bqhB[kc], SB[t]);
                    SB[t] = MFMA16(kl8, bqhB[kc], SB[t]);
                    SB[t] = MFMA16(kh8, bqlB[kc], SB[t]);
                    SA[t] = MFMA16(kh8, bqhA[kc], SA[t]);
                    SA[t] = MFMA16(kl8, bqhA[kc], SA[t]);
                    SA[t] = MFMA16(kh8, bqlA[kc], SA[t]);
                }
        } else {
            #pragma unroll
            for (int t = 0; t < 4; t++)
                #pragma unroll
                for (int kc = 0; kc < 2; kc++) {
                    s16x8 kh8 = *(const s16x8*)&Ksh[t * 16 + lm][(kc * 32 + quad * 8) ^ swz];
                    s16x8 kl8 = *(const s16x8*)&Ksl[t * 16 + lm][(kc * 32 + quad * 8) ^ swz];
                    SB[t] = MFMA16(kh8, bqhB[kc], SB[t]);
                    SB[t] = MFMA16(kl8, bqhB[kc], SB[t]);
                    SB[t] = MFMA16(kh8, bqlB[kc], SB[t]);
                }
        }

        // causal masks (scale pre-folded into Q)
        if (kt == qtB) {
            #pragma unroll
            for (int t = 0; t < 4; t++)
                #pragma unroll
                for (int r = 0; r < 4; r++)
                    if ((t * 16 + quad * 4 + r) > qg) SB[t][r] = -INFINITY;
        }
        if (kt == qtA) {
            #pragma unroll
            for (int t = 0; t < 4; t++)
                #pragma unroll
                for (int r = 0; r < 4; r++)
                    if ((t * 16 + quad * 4 + r) > qg) SA[t][r] = -INFINITY;
        }

        // ---- softmax (dual chains are independent) ----
        online_sm(SB, mB, lB, OB, quad);
        if (doA) online_sm(SA, mA, lA, OA, quad);

        // ---- P^T -> Ps (truncating bf16; P in [0, 256]) ----
        #pragma unroll
        for (int t = 0; t < 4; t++) {
            s16x4 p;
            #pragma unroll
            for (int r = 0; r < 4; r++)
                p[r] = (short)(__float_as_uint(SB[t][r]) >> 16);
            *(s16x4*)&Ps[wave][0][lm][(t * 16 + quad * 4) ^ swz] = p;
        }
        if (doA) {
            #pragma unroll
            for (int t = 0; t < 4; t++) {
                s16x4 p;
                #pragma unroll
                for (int r = 0; r < 4; r++)
                    p[r] = (short)(__float_as_uint(SA[t][r]) >> 16);
                *(s16x4*)&Ps[wave][1][lm][(t * 16 + quad * 4) ^ swz] = p;
            }
        }
        // wave-private slabs: no barrier (lgkmcnt ordering within wave)

        // ---- O += P V: shared Vt frag feeds both tiles ----
        s16x8 apB[2], apA[2];
        #pragma unroll
        for (int kc = 0; kc < 2; kc++)
            apB[kc] = *(const s16x8*)&Ps[wave][0][lm][(kc * 32 + quad * 8) ^ swz];
        if (doA) {
            #pragma unroll
            for (int kc = 0; kc < 2; kc++)
                apA[kc] = *(const s16x8*)&Ps[wave][1][lm][(kc * 32 + quad * 8) ^ swz];
            #pragma unroll
            for (int t = 0; t < 4; t++)
                #pragma unroll
                for (int kc = 0; kc < 2; kc++) {
                    s16x8 bv = *(const s16x8*)&Vt[t * 16 + lm][(kc * 32 + quad * 8) ^ swz];
                    OB[t] = MFMA16(apB[kc], bv, OB[t]);
                    OA[t] = MFMA16(apA[kc], bv, OA[t]);
                }
        } else {
            #pragma unroll
            for (int t = 0; t < 4; t++)
                #pragma unroll
                for (int kc = 0; kc < 2; kc++) {
                    s16x8 bv = *(const s16x8*)&Vt[t * 16 + lm][(kc * 32 + quad * 8) ^ swz];
                    OB[t] = MFMA16(apB[kc], bv, OB[t]);
                }
        }
    }

    // ---- epilogue: O row q = wave*16+quad*4+r, col d = t*16+lm ----
    float liA[4], liB[4];
    #pragma unroll
    for (int r = 0; r < 4; r++) {
        liA[r] = 1.0f / __shfl(lA, quad * 4 + r, 64);
        liB[r] = 1.0f / __shfl(lB, quad * 4 + r, 64);
    }
    #pragma unroll
    for (int t = 0; t < 4; t++)
        #pragma unroll
        for (int r = 0; r < 4; r++) {
            int d  = t * 16 + lm;
            int qa = q0A + wave * 16 + quad * 4 + r;
            int qb = q0B + wave * 16 + quad * 4 + r;
            Yb[((size_t)b * T_ + qa) * C_ + h * D_ + d] =
                (short)f2b(OA[t][r] * liA[r]);
            Yb[((size_t)b * T_ + qb) * C_ + h * D_ + d] =
                (short)f2b(OB[t][r] * liB[r]);
        }
}

// ---------------------------------------------------------------------------
extern "C" void kernel_launch(void* const* d_in, const int* in_sizes, int n_in,
                              void* d_out, int out_size, void* d_ws, size_t ws_size,
                              hipStream_t stream)
{
    const float* x      = (const float*)d_in[0];
    const float* W_attn = (const float*)d_in[1];
    const float* b_attn = (const float*)d_in[2];
    const float* W_proj = (const float*)d_in[3];
    const float* b_proj = (const float*)d_in[4];
    float* out = (float*)d_out;

    char* ws = (char*)d_ws;
    const size_t MB = 1024 * 1024;
    short* Qh   = (short*)(ws);            // 8 MB  [ 0, 8)
    short* Ql   = (short*)(ws +  8 * MB);  // 8 MB  [ 8,16)
    short* Kh   = (short*)(ws + 16 * MB);  // 8 MB  [16,24)
    short* Kl   = (short*)(ws + 24 * MB);  // 8 MB  [24,32)
    short* xh   = (short*)(ws + 32 * MB);  // 8 MB  [32,40)  dead after qkv_v
    short* xl   = (short*)(ws + 40 * MB);  // 8 MB  [40,48)  dead after qkv_qk
    short* WaTh = (short*)(ws + 48 * MB);  // 6 MB  [48,54)
    short* WaTl = (short*)(ws + 54 * MB);  // 6 MB  [54,60)
    short* WpT  = (short*)(ws + 60 * MB);  // 2 MB  [60,62)
    short* VT   = (short*)(ws + 40 * MB);  // 8 MB  aliases xl (born at qkv_v)
    short* Yb   = (short*)(ws + 32 * MB);  // 8 MB  aliases xh (born at attn)

    cvt_split <<<dim3(M_ * C_ / 2048), 256, 0, stream>>>(x, xh, xl, M_ * C_);
    cvtT_split<<<dim3(N3_ / 64, C_ / 64), 256, 0, stream>>>(W_attn, WaTh, WaTl, C_, N3_);
    cvtT_bf16 <<<dim3(C_ / 64, C_ / 64), 256, 0, stream>>>(W_proj, WpT, C_, C_);

    qkv_qk <<<dim3(16, 32), 256, 0, stream>>>(xh, xl, WaTh, WaTl, b_attn,
                                              Qh, Ql, Kh, Kl);
    qkv_v  <<<dim3(8, 64), 256, 0, stream>>>(xh, WaTh + (size_t)2048 * C_,
                                             b_attn + 2048, VT);
    attn_mfma<<<dim3(512), 256, 0, stream>>>(Qh, Ql, Kh, Kl, VT, Yb);
    proj_mfma<<<dim3(8, 64), 256, 0, stream>>>(Yb, WpT, b_proj, out);
}